// Round 6
// baseline (1568.918 us; speedup 1.0000x reference)
//
#include <hip/hip_runtime.h>
#include <math.h>

typedef unsigned short U16;
typedef unsigned int   U32;
typedef __attribute__((ext_vector_type(8))) __bf16 bf16x8;
typedef __attribute__((ext_vector_type(4))) float  f32x4;

__device__ __forceinline__ U16 f2bf(float f) {
    __bf16 h = (__bf16)f;
    return __builtin_bit_cast(U16, h);
}
__device__ __forceinline__ float gelu_f(float y) {
    return 0.5f * y * (1.0f + erff(y * 0.70710678118654752f));
}

#define XT_S  69     // fp32 x-tile row stride (68 cols + 1 pad)
#define XT_CS 207    // 3 * XT_S, per-channel stride
#define ELS   40     // El per-pixel channel stride (32 ch + 8 pad) -> 80 B, 16B-aligned

// ---------------- K1: edge maps + 4 branch GEMMs + BN + GELU + pooled ----------------
// All global I/O fp32. ef layout [b][c][pix] (== output layout, lives in d_out).
__global__ __launch_bounds__(256, 2)
void k1_branch(const float* __restrict__ x, const float* __restrict__ wB,
               const float* __restrict__ bB, const float* __restrict__ bg,
               const float* __restrict__ bbt, float* __restrict__ ef,
               float* __restrict__ pooled)
{
    __shared__ float xs[32 * XT_CS];   // 26496 B
    __shared__ U16   El[4 * 64 * ELS]; // 20480 B
    const int tid  = threadIdx.x;
    const int bi   = blockIdx.x;
    const int b    = bi >> 8;
    const int rem  = bi & 255;
    const int h    = rem >> 1;
    const int w0   = (rem & 1) << 6;
    const int lane = tid & 63;
    const int wv   = tid >> 6;          // wave = branch id (sobel,lap,diag,grad)
    const int l15  = lane & 15;
    const int quad = lane >> 4;
    const int ec   = tid & 31;          // E-compute: channel within chunk
    const int px0  = (tid >> 5) * 8;    // E-compute: 8-pixel group

    f32x4 acc[8][4];
#pragma unroll
    for (int i = 0; i < 8; ++i)
#pragma unroll
        for (int j = 0; j < 4; ++j) {
            f32x4 z = {0.f, 0.f, 0.f, 0.f};
            acc[i][j] = z;
        }

#pragma unroll 1
    for (int ch = 0; ch < 16; ++ch) {
        const int cbase = ch * 32;
        // ---- stage x tile: 32 ch x 3 rows x 68 cols, fp32 ----
        for (int i = tid; i < 6528; i += 256) {
            int c  = i / 204;
            int r2 = i - c * 204;
            int r  = r2 / 68;
            int d  = r2 - r * 68;
            int hg  = h + r - 1;
            int col = w0 - 2 + d;
            float val = 0.f;
            if (hg >= 0 && hg < 128 && col >= 0 && col < 128)
                val = x[(((b * 512 + cbase + c) * 128 + hg) << 7) + col];
            xs[c * XT_CS + r * XT_S + d] = val;
        }
        __syncthreads();
        // ---- compute E (sobel, lap, diag, grad) in fp32 -> El bf16 ----
        {
            const int base = ec * XT_CS;
#pragma unroll 1
            for (int i = 0; i < 8; ++i) {
                const int px = px0 + i;
                float v[3][3];
#pragma unroll
                for (int r = 0; r < 3; ++r)
#pragma unroll
                    for (int jj = 0; jj < 3; ++jj)
                        v[r][jj] = xs[base + r * XT_S + px + 1 + jj];
                float gh = (v[0][2] - v[0][0]) + 2.f * (v[1][2] - v[1][0]) + (v[2][2] - v[2][0]);
                float gv = (v[2][0] + 2.f * v[2][1] + v[2][2]) - (v[0][0] + 2.f * v[0][1] + v[0][2]);
                float lp = v[0][1] + v[1][0] + v[1][2] + v[2][1] - 4.f * v[1][1];
                float d1 = v[0][0] - v[0][2] - v[2][0] + v[2][2];
                float sob = sqrtf(gh * gh + gv * gv + 1e-8f);
                float lav = fabsf(lp);
                float dia = fabsf(d1);   // K_D2 == -K_D1 -> max(|d1|,|d2|) = |d1|
                float grd = sqrtf(sob * sob + lav * lav + 1e-8f);
                El[(0 * 64 + px) * ELS + ec] = f2bf(sob);
                El[(1 * 64 + px) * ELS + ec] = f2bf(lav);
                El[(2 * 64 + px) * ELS + ec] = f2bf(dia);
                El[(3 * 64 + px) * ELS + ec] = f2bf(grd);
            }
        }
        __syncthreads();
        // ---- per-wave GEMM (one 32-wide k-step): feat[o][px] += W[o][c]*E[px][c] ----
        {
            const int cg = quad * 8;    // k-offset within chunk
            bf16x8 bfr[4];
#pragma unroll
            for (int nt = 0; nt < 4; ++nt)
                bfr[nt] = *(const bf16x8*)&El[(wv * 64 + nt * 16 + l15) * ELS + cg];
#pragma unroll
            for (int mt = 0; mt < 8; ++mt) {
                const float* wrow = &wB[(wv * 128 + mt * 16 + l15) * 512 + cbase + cg];
                f32x4 wa = *(const f32x4*)wrow;
                f32x4 wb4 = *(const f32x4*)(wrow + 4);
                bf16x8 a;
                a[0] = (__bf16)wa[0]; a[1] = (__bf16)wa[1];
                a[2] = (__bf16)wa[2]; a[3] = (__bf16)wa[3];
                a[4] = (__bf16)wb4[0]; a[5] = (__bf16)wb4[1];
                a[6] = (__bf16)wb4[2]; a[7] = (__bf16)wb4[3];
#pragma unroll
                for (int nt = 0; nt < 4; ++nt)
                    acc[mt][nt] = __builtin_amdgcn_mfma_f32_16x16x32_bf16(a, bfr[nt], acc[mt][nt], 0, 0, 0);
            }
        }
        __syncthreads();
    }
    // ---- epilogue: BN(eval) + GELU, store ef fp32, pooled partials ----
    const int pixbase = h * 128 + w0;
#pragma unroll 1
    for (int mt = 0; mt < 8; ++mt) {
        const int ob = wv * 128 + mt * 16 + quad * 4;   // concat channel base for 4 regs
        float s[4], sh[4], ps[4];
#pragma unroll
        for (int r = 0; r < 4; ++r) {
            float sc = bg[ob + r] * 0.9999950000374997f;   // 1/sqrt(1+1e-5)
            s[r] = sc; sh[r] = bB[ob + r] * sc + bbt[ob + r]; ps[r] = 0.f;
        }
#pragma unroll
        for (int nt = 0; nt < 4; ++nt) {
            const int px = nt * 16 + l15;
#pragma unroll
            for (int r = 0; r < 4; ++r) {
                float y = acc[mt][nt][r] * s[r] + sh[r];
                float f = gelu_f(y);
                ps[r] += f;
                ef[(size_t)(b * 512 + ob + r) * 16384 + pixbase + px] = f;
            }
        }
#pragma unroll
        for (int r = 0; r < 4; ++r)
#pragma unroll
            for (int off = 1; off < 16; off <<= 1)
                ps[r] += __shfl_xor(ps[r], off, 64);
        if (l15 == 0) {
#pragma unroll
            for (int r = 0; r < 4; ++r)
                atomicAdd(&pooled[b * 512 + ob + r], ps[r]);
        }
    }
}

// ---------------- K2: SE attention (tiny, fp32) ----------------
__global__ void k2_att(const float* __restrict__ pooled,
                       const float* __restrict__ w1, const float* __restrict__ b1,
                       const float* __restrict__ w2, const float* __restrict__ b2,
                       float* __restrict__ att)
{
    __shared__ float pl[2048];
    __shared__ float hb[256];
    const int t = threadIdx.x;
    for (int i = t; i < 2048; i += 256) pl[i] = pooled[i] * (1.0f / 16384.0f);
    __syncthreads();
    {
        const int bb = t >> 6, e = t & 63;
        float a = b1[e];
        const float* wr = w1 + e * 512;
        for (int c = 0; c < 512; ++c)
            a += pl[bb * 512 + c] * wr[c];
        hb[t] = gelu_f(a);
    }
    __syncthreads();
    for (int i = t; i < 2048; i += 256) {
        const int bb = i >> 9, c = i & 511;
        const float* wr = w2 + c * 64;
        float a = b2[c];
        for (int e = 0; e < 64; ++e)
            a += hb[bb * 64 + e] * wr[e];
        att[i] = 1.0f / (1.0f + __expf(-a));
    }
}

// ---------------- K3: stage ef(xatt)->LDS bf16 transpose, GEMM + LN + GELU + residual ----------------
#define L3W 260   // U32 per LDS pixel row (256 c-pairs + 4 pad; 1040 B)

__global__ __launch_bounds__(256, 2)
void k3_fuse(const float* __restrict__ ef, const float* __restrict__ att,
             const float* __restrict__ wf, const float* __restrict__ bfu,
             const float* __restrict__ lng, const float* __restrict__ lnb,
             const float* __restrict__ x, float* __restrict__ out)
{
    __shared__ U32 sh32[64 * L3W];          // 66560 B
    __shared__ float red_s[256];
    __shared__ float red_q[256];
    __shared__ float mu_s[64];
    __shared__ float iv_s[64];
    const int tid  = threadIdx.x, bi = blockIdx.x;
    const int b    = bi >> 8;
    const int pix0 = (bi & 255) << 6;
    const int lane = tid & 63, wv = tid >> 6;
    const int l15  = lane & 15, quad = lane >> 4;

    // ---- stage: read fp32 ef [b][c][pix] (64 px, all 512 c), scale by att,
    //      convert to bf16, transpose into LDS [px][c-pair] ----
    {
        const int c0 = 2 * tid;
        const float a0 = att[b * 512 + c0];
        const float a1 = att[b * 512 + c0 + 1];
        const float* r0p = ef + (size_t)(b * 512 + c0) * 16384 + pix0;
        const float* r1p = r0p + 16384;
#pragma unroll 1
        for (int p4 = 0; p4 < 16; ++p4) {
            f32x4 va = *(const f32x4*)(r0p + p4 * 4);
            f32x4 vb = *(const f32x4*)(r1p + p4 * 4);
#pragma unroll
            for (int i = 0; i < 4; ++i) {
                U16 sa = f2bf(va[i] * a0);
                U16 sb = f2bf(vb[i] * a1);
                sh32[(p4 * 4 + i) * L3W + tid] = (U32)sa | ((U32)sb << 16);
            }
        }
    }
    __syncthreads();

    f32x4 acc[4][8];
#pragma unroll
    for (int i = 0; i < 4; ++i)
#pragma unroll
        for (int j = 0; j < 8; ++j) {
            f32x4 z = {0.f, 0.f, 0.f, 0.f};
            acc[i][j] = z;
        }
#pragma unroll 1
    for (int ks = 0; ks < 16; ++ks) {
        const int cg = ks * 32 + quad * 8;
        bf16x8 a[4];
#pragma unroll
        for (int mt = 0; mt < 4; ++mt)
            a[mt] = *(const bf16x8*)&sh32[(mt * 16 + l15) * L3W + (cg >> 1)];
#pragma unroll
        for (int nt = 0; nt < 8; ++nt) {
            const float* wrow = &wf[(size_t)(wv * 128 + nt * 16 + l15) * 512 + cg];
            f32x4 w0v = *(const f32x4*)wrow;
            f32x4 w1v = *(const f32x4*)(wrow + 4);
            bf16x8 bw;
            bw[0] = (__bf16)w0v[0]; bw[1] = (__bf16)w0v[1];
            bw[2] = (__bf16)w0v[2]; bw[3] = (__bf16)w0v[3];
            bw[4] = (__bf16)w1v[0]; bw[5] = (__bf16)w1v[1];
            bw[6] = (__bf16)w1v[2]; bw[7] = (__bf16)w1v[3];
#pragma unroll
            for (int mt = 0; mt < 4; ++mt)
                acc[mt][nt] = __builtin_amdgcn_mfma_f32_16x16x32_bf16(a[mt], bw, acc[mt][nt], 0, 0, 0);
        }
    }
    // bias then LN stats (sum, sumsq over all 512 channels per pixel)
#pragma unroll
    for (int nt = 0; nt < 8; ++nt) {
        const float bz = bfu[wv * 128 + nt * 16 + l15];
#pragma unroll
        for (int mt = 0; mt < 4; ++mt)
#pragma unroll
            for (int r = 0; r < 4; ++r)
                acc[mt][nt][r] += bz;
    }
#pragma unroll
    for (int mt = 0; mt < 4; ++mt)
#pragma unroll
        for (int r = 0; r < 4; ++r) {
            float s = 0.f, q = 0.f;
#pragma unroll
            for (int nt = 0; nt < 8; ++nt) {
                float v = acc[mt][nt][r];
                s += v; q += v * v;
            }
#pragma unroll
            for (int off = 1; off < 16; off <<= 1) {
                s += __shfl_xor(s, off, 64);
                q += __shfl_xor(q, off, 64);
            }
            if (l15 == 0) {
                const int p = mt * 16 + quad * 4 + r;
                red_s[p * 4 + wv] = s;
                red_q[p * 4 + wv] = q;
            }
        }
    __syncthreads();
    if (tid < 64) {
        float S = red_s[tid * 4] + red_s[tid * 4 + 1] + red_s[tid * 4 + 2] + red_s[tid * 4 + 3];
        float Q = red_q[tid * 4] + red_q[tid * 4 + 1] + red_q[tid * 4 + 2] + red_q[tid * 4 + 3];
        float mu  = S * (1.0f / 512.0f);
        float var = fmaxf(Q * (1.0f / 512.0f) - mu * mu, 0.0f);
        mu_s[tid] = mu;
        iv_s[tid] = rsqrtf(var + 1e-6f);
    }
    __syncthreads();
#pragma unroll 1
    for (int nt = 0; nt < 8; ++nt) {
        const int o = wv * 128 + nt * 16 + l15;
        const float g  = lng[o];
        const float be = lnb[o];
        const size_t rowoff = (size_t)(b * 512 + o) * 16384 + pix0;
#pragma unroll
        for (int mt = 0; mt < 4; ++mt) {
            const int pb = mt * 16 + quad * 4;
            f32x4 xv = *(const f32x4*)&x[rowoff + pb];
            f32x4 ov;
#pragma unroll
            for (int r = 0; r < 4; ++r) {
                const int p = pb + r;
                float z = (acc[mt][nt][r] - mu_s[p]) * iv_s[p];
                float y = z * g + be;
                ov[r] = gelu_f(y) + xv[r];
            }
            *(f32x4*)&out[rowoff + pb] = ov;
        }
    }
}

extern "C" void kernel_launch(void* const* d_in, const int* in_sizes, int n_in,
                              void* d_out, int out_size, void* d_ws, size_t ws_size,
                              hipStream_t stream)
{
    // Reference dtypes are ALL float32 (jnp.float32 everywhere in setup_inputs).
    const float* x   = (const float*)d_in[0];
    const float* wB  = (const float*)d_in[1];
    const float* bB  = (const float*)d_in[2];
    const float* bg  = (const float*)d_in[3];
    const float* bbt = (const float*)d_in[4];
    const float* w1  = (const float*)d_in[5];
    const float* b1  = (const float*)d_in[6];
    const float* w2  = (const float*)d_in[7];
    const float* b2  = (const float*)d_in[8];
    const float* wf  = (const float*)d_in[9];
    const float* bfu = (const float*)d_in[10];
    const float* lng = (const float*)d_in[11];
    const float* lnb = (const float*)d_in[12];
    float* out = (float*)d_out;

    // ef intermediate (fp32, [b][c][pix] == output layout) lives in d_out:
    // K3 blocks read exactly the region they later overwrite (in-place safe).
    // d_ws usage: only 16 KiB (pooled 8K + att 8K).
    float* ef     = out;
    float* pooled = (float*)d_ws;
    float* att    = (float*)((char*)d_ws + 8192);

    hipMemsetAsync(pooled, 0, 2048 * sizeof(float), stream);
    hipLaunchKernelGGL(k1_branch, dim3(1024), dim3(256), 0, stream,
                       x, wB, bB, bg, bbt, ef, pooled);
    hipLaunchKernelGGL(k2_att, dim3(1), dim3(256), 0, stream,
                       pooled, w1, b1, w2, b2, att);
    hipLaunchKernelGGL(k3_fuse, dim3(1024), dim3(256), 0, stream,
                       ef, att, wf, bfu, lng, lnb, x, out);
}